// Round 7
// baseline (306.925 us; speedup 1.0000x reference)
//
#include <hip/hip_runtime.h>

// GMLoss: bidirectional chamfer min + Geman-McClure penalty (MU=1).
// srcs, tgts: [B=8, D=3, N=4096] fp32. Output: scalar fp32.
//
// R7: fused 2-kernel structure. R6's math was right (absmax 0) but ~50us of
// kernel time remained: launch gaps, 16MB partials round-trip, depth-1
// prefetch stalls. Changes:
//  - d_tgt col-mins -> 128KB uint cells via atomicMin on float bits (valid
//    for clamped >=0 values: IEEE order == uint order). Kills the 16MB
//    write + latency-bound strided re-read + one launch.
//  - 64-row blocks (512 thr, 8 waves; wave = 16 col-tiles x 2 row-tiles):
//    2 MFMAs per B-load, half the atomic traffic of 32-row blocks.
//  - Depth-4 B-frag register prefetch ring (~2200 cyc cover vs ~900 HBM).
//  - Ticketed finish inside chamfer: per-batch last block (threadfence +
//    ticket) reduces its 4096 cells (atomicMin-as-coherent-read), global
//    ticket's last block writes the scalar. No reduce/write kernels.
// K=13 packing (R6-verified, absmax 0):
//   A: [-2sh(3) -2sl(3) -2sh(2/3)... | pattern below], B matched so that
//   dot = -2sh.th -2sl.th -2sh.tl + s2h+s2l + t2h+t2l  (exact P tile, no C).
// Layouts (m74/m101): A[m=lane&31][k=(lane>>5)*8+j], B same (n=lane&31);
// D: col=lane&31, row=(reg&3)+8*(reg>>2)+4*(lane>>5).

#define NPTS 4096
#define NB   8

typedef __attribute__((ext_vector_type(8)))  short bf16x8;
typedef __attribute__((ext_vector_type(16))) float floatx16;

#define OFF_APACK 0u
#define OFF_BPACK (1u << 20)
#define OFF_CELLS (2u << 20)
#define OFF_ACC   ((2u << 20) + (128u << 10))

union V16 { int4 i; bf16x8 h; };

__device__ __forceinline__ unsigned short f2bf(float f) {
    unsigned u = __float_as_uint(f);
    u += 0x7FFFu + ((u >> 16) & 1u);       // RNE
    return (unsigned short)(u >> 16);
}
__device__ __forceinline__ float bf2f(unsigned short h) {
    return __uint_as_float(((unsigned)h) << 16);
}
__device__ __forceinline__ int pk(unsigned short lo, unsigned short hi) {
    return (int)((unsigned)lo | ((unsigned)hi << 16));
}

// ---------------- Kernel 1: pack K=13 operands + init cells/acc ----------
__global__ __launch_bounds__(256)
void transform_kernel(const float* __restrict__ srcs,
                      const float* __restrict__ tgts,
                      char* __restrict__ ws) {
    const int gid = blockIdx.x * 256 + threadIdx.x;   // b*4096 + j
    const int b = gid >> 12, j = gid & 4095;
    const unsigned short ONE = 0x3F80;

    {   // ---- src -> Apack ----
        const float* sp = srcs + b * 3 * NPTS;
        const float x = sp[j], y = sp[NPTS + j], z = sp[2 * NPTS + j];
        const unsigned short hx = f2bf(x), hy = f2bf(y), hz = f2bf(z);
        const unsigned short a0 = f2bf(-2.0f * bf2f(hx));
        const unsigned short a1 = f2bf(-2.0f * bf2f(hy));
        const unsigned short a2 = f2bf(-2.0f * bf2f(hz));
        const unsigned short l0 = f2bf(-2.0f * (x - bf2f(hx)));
        const unsigned short l1 = f2bf(-2.0f * (y - bf2f(hy)));
        const unsigned short l2 = f2bf(-2.0f * (z - bf2f(hz)));
        const float s2 = fmaf(z, z, fmaf(y, y, x * x));
        const unsigned short s2h = f2bf(s2);
        const unsigned short s2l = f2bf(s2 - bf2f(s2h));
        int4* Ap = (int4*)(ws + OFF_APACK + (size_t)gid * 32);
        Ap[0] = make_int4(pk(a0, a1), pk(a2, l0), pk(l1, l2), pk(a0, a1));
        Ap[1] = make_int4(pk(a2, s2h), pk(s2l, ONE), pk(ONE, 0), 0);
    }
    {   // ---- tgt -> Bpack ----
        const float* tp = tgts + b * 3 * NPTS;
        const float x = tp[j], y = tp[NPTS + j], z = tp[2 * NPTS + j];
        const unsigned short hx = f2bf(x), hy = f2bf(y), hz = f2bf(z);
        const unsigned short lx = f2bf(x - bf2f(hx));
        const unsigned short ly = f2bf(y - bf2f(hy));
        const unsigned short lz = f2bf(z - bf2f(hz));
        const float t2 = fmaf(z, z, fmaf(y, y, x * x));
        const unsigned short t2h = f2bf(t2);
        const unsigned short t2l = f2bf(t2 - bf2f(t2h));
        int4* Bp = (int4*)(ws + OFF_BPACK + (size_t)gid * 32);
        Bp[0] = make_int4(pk(hx, hy), pk(hz, hx), pk(hy, hz), pk(lx, ly));
        Bp[1] = make_int4(pk(lz, ONE), pk(ONE, t2h), pk(t2l, 0), 0);
    }
    // ---- init d_tgt cells (+inf) and accumulators ----
    ((unsigned*)(ws + OFF_CELLS))[gid] = 0x7F800000u;   // 32768 cells exactly
    if (gid == 0) {
        float* acc = (float*)(ws + OFF_ACC);
        acc[0] = 0.0f;                                  // GM sum
        unsigned* u = (unsigned*)(ws + OFF_ACC);
#pragma unroll
        for (int k = 1; k <= 9; k++) u[k] = 0u;         // tickets[8] + gticket
    }
}

// ---------------- Kernel 2: fused MFMA chamfer + ticketed reduce ----------
#define PROC(T, IDX)                                                         \
    {                                                                        \
        const floatx16 d0 =                                                  \
            __builtin_amdgcn_mfma_f32_32x32x16_bf16(av0.h, (T).h, zero, 0, 0, 0); \
        const floatx16 d1 =                                                  \
            __builtin_amdgcn_mfma_f32_32x32x16_bf16(av1.h, (T).h, zero, 0, 0, 0); \
        float m0 = 3.0e38f, m1 = 3.0e38f;                                    \
        _Pragma("unroll")                                                    \
        for (int r = 0; r < 16; r++) {                                       \
            rmin0[r] = fminf(rmin0[r], d0[r]);                               \
            rmin1[r] = fminf(rmin1[r], d1[r]);                               \
            m0 = fminf(m0, d0[r]);                                           \
            m1 = fminf(m1, d1[r]);                                           \
        }                                                                    \
        float cmin = fminf(m0, m1);                                          \
        cmin = fminf(cmin, __shfl_xor(cmin, 32, 64));                        \
        cmin = fmaxf(cmin, 0.0f);                                            \
        if (lane < 32)                                                       \
            atomicMin(&cells[(ct0 + (IDX)) * 32 + l31],                      \
                      __float_as_uint(cmin));                                \
    }

__global__ __launch_bounds__(512, 4)
void chamfer_kernel(char* __restrict__ ws, float* __restrict__ out) {
    const int blk    = blockIdx.x;        // 0..511
    const int b      = blk >> 6;
    const int stripe = blk & 63;          // 64 src rows
    const int tid    = threadIdx.x;
    const int wave   = tid >> 6;          // 0..7
    const int lane   = tid & 63;
    const int l31    = lane & 31;
    const int half   = lane >> 5;

    const char* Ap = ws + OFF_APACK;
    const char* Bp = ws + OFF_BPACK;
    unsigned* cells   = (unsigned*)(ws + OFF_CELLS) + b * NPTS;
    float*    acc     = (float*)(ws + OFF_ACC);
    unsigned* tickets = (unsigned*)(ws + OFF_ACC) + 1;    // [8]
    unsigned* gticket = (unsigned*)(ws + OFF_ACC) + 9;

    V16 av0, av1;
    av0.i = *(const int4*)(Ap + (size_t)(b * NPTS + stripe * 64 + l31) * 32 + half * 16);
    av1.i = *(const int4*)(Ap + (size_t)(b * NPTS + stripe * 64 + 32 + l31) * 32 + half * 16);

    floatx16 rmin0, rmin1, zero;
#pragma unroll
    for (int r = 0; r < 16; r++) { rmin0[r] = 3.0e38f; rmin1[r] = 3.0e38f; zero[r] = 0.0f; }

    const int ct0 = wave * 16;            // 16 col-tiles per wave
    const char* bbase = Bp + (size_t)(b * NPTS + ct0 * 32 + l31) * 32 + half * 16;

    // depth-4 prefetch ring (tail loads past tile 15 read in-ws garbage, unused)
    V16 t0, t1, t2, t3;
    t0.i = *(const int4*)(bbase);
    t1.i = *(const int4*)(bbase + 1024);
    t2.i = *(const int4*)(bbase + 2048);
    t3.i = *(const int4*)(bbase + 3072);

#pragma unroll
    for (int i = 0; i < 16; i += 4) {
        V16 n0, n1, n2, n3;
        n0.i = *(const int4*)(bbase + (size_t)(i + 4) * 1024);
        n1.i = *(const int4*)(bbase + (size_t)(i + 5) * 1024);
        n2.i = *(const int4*)(bbase + (size_t)(i + 6) * 1024);
        n3.i = *(const int4*)(bbase + (size_t)(i + 7) * 1024);
        PROC(t0, i + 0) PROC(t1, i + 1) PROC(t2, i + 2) PROC(t3, i + 3)
        t0 = n0; t1 = n1; t2 = n2; t3 = n3;
    }

    // ---- d_src: butterfly min over the 32 col-lanes ----
#pragma unroll
    for (int off = 1; off < 32; off <<= 1) {
#pragma unroll
        for (int r = 0; r < 16; r++) {
            rmin0[r] = fminf(rmin0[r], __shfl_xor(rmin0[r], off, 64));
            rmin1[r] = fminf(rmin1[r], __shfl_xor(rmin1[r], off, 64));
        }
    }
    __shared__ float sRow[8][64];
    __shared__ float sRed[8];
    __shared__ unsigned sLast;
    if (l31 == 0) {                       // lanes 0 and 32
#pragma unroll
        for (int r = 0; r < 16; r++) {
            const int row = (r & 3) + 8 * (r >> 2) + 4 * half;
            sRow[wave][row]      = rmin0[r];
            sRow[wave][32 + row] = rmin1[r];
        }
    }
    __syncthreads();
    if (tid < 64) {
        float m = 3.0e38f;
#pragma unroll
        for (int w = 0; w < 8; w++) m = fminf(m, sRow[w][tid]);
        m = fmaxf(m, 0.0f);
        float g = m / (m + 1.0f);         // GM, MU=1
#pragma unroll
        for (int off = 1; off < 64; off <<= 1)
            g += __shfl_xor(g, off, 64);
        if (tid == 0) {
            atomicAdd(acc, g);
            __threadfence();
            const unsigned old = atomicAdd(&tickets[b], 1u);
            sLast = (old == 63u) ? 1u : 0u;
        }
    }
    __syncthreads();

    // ---- per-batch last block: fold this batch's 4096 d_tgt cells ----
    if (sLast) {
        __threadfence();
        float gt = 0.0f;
#pragma unroll
        for (int k = 0; k < 8; k++) {     // atomicMin(+inf) = coherent read
            const unsigned u = atomicMin(&cells[k * 512 + tid], 0x7F800000u);
            const float m = __uint_as_float(u);
            gt += m / (m + 1.0f);
        }
#pragma unroll
        for (int off = 1; off < 64; off <<= 1)
            gt += __shfl_xor(gt, off, 64);
        if (lane == 0) sRed[wave] = gt;
        __syncthreads();
        if (tid == 0) {
            float tot = 0.0f;
#pragma unroll
            for (int w = 0; w < 8; w++) tot += sRed[w];
            atomicAdd(acc, tot);
            __threadfence();
            const unsigned o2 = atomicAdd(gticket, 1u);
            if (o2 == NB - 1) {           // very last: exact final write
                const float total = atomicAdd(acc, 0.0f);
                out[0] = total * (1.0f / (NB * NPTS));
            }
        }
    }
}

extern "C" void kernel_launch(void* const* d_in, const int* in_sizes, int n_in,
                              void* d_out, int out_size, void* d_ws, size_t ws_size,
                              hipStream_t stream) {
    const float* srcs = (const float*)d_in[0];
    const float* tgts = (const float*)d_in[1];
    float* out = (float*)d_out;
    char* ws = (char*)d_ws;

    transform_kernel<<<dim3(128), dim3(256), 0, stream>>>(srcs, tgts, ws);
    chamfer_kernel<<<dim3(512), dim3(512), 0, stream>>>(ws, out);
}

// Round 8
// 80.385 us; speedup vs baseline: 3.8182x; 3.8182x over previous
//
#include <hip/hip_runtime.h>

// GMLoss: bidirectional chamfer min + Geman-McClure penalty (MU=1).
// srcs, tgts: [B=8, D=3, N=4096] fp32. Output: scalar fp32.
//
// R8: two row-min-only MFMA passes (one per direction) instead of one pass
// producing both row- and col-mins. R7 proved bulk device atomics are fatal
// (2M atomicMin -> 478MB write traffic, 263us); R6's single-pass needed a
// 16MB partials round-trip + a 16-min tree/shfl/store per MFMA for d_tgt.
// With swapped-role passes the inner loop is ONLY: b128 load (depth-4 ring),
// 2 MFMA, 32 v_min. No partials, no atomics, no trees. Both directions exit
// as per-block GM sums -> plain stores to bsum[1024] -> 1-block finish.
// MFMA count doubles to 262k = 2048 cyc/SIMD (trivial vs VALU).
//
// K=13 packing (R6-verified, absmax 0.0):
//   A k: [-2sh_x,-2sh_y,-2sh_z, -2sl_x,-2sl_y,-2sl_z, -2sh_x,-2sh_y,-2sh_z,
//         s2h, s2l, 1, 1, 0, 0, 0]
//   B k: [ th_x, th_y, th_z,  th_x, th_y, th_z,  tl_x, tl_y, tl_z,
//         1, 1, t2h, t2l, 0, 0, 0]
//   dot = |s|^2+|t|^2-2s.t (dropped sl.tl ~1e-5 << 1.26e-3 threshold).
// Layouts (m74/m101): A[m=lane&31][k=(lane>>5)*8+j], B same (n=lane&31);
// D: col=lane&31, row=(reg&3)+8*(reg>>2)+4*(lane>>5).

#define NPTS 4096
#define NB   8

typedef __attribute__((ext_vector_type(8)))  short bf16x8;
typedef __attribute__((ext_vector_type(16))) float floatx16;

// ws layout: Apack[srcs], Apack[tgts], Bpack[srcs], Bpack[tgts], bsum
#define OFF_APACK_S 0u
#define OFF_APACK_T (1u << 20)
#define OFF_BPACK_S (2u << 20)
#define OFF_BPACK_T (3u << 20)
#define OFF_BSUM    (4u << 20)

union V16 { int4 i; bf16x8 h; };

__device__ __forceinline__ unsigned short f2bf(float f) {
    unsigned u = __float_as_uint(f);
    u += 0x7FFFu + ((u >> 16) & 1u);       // RNE
    return (unsigned short)(u >> 16);
}
__device__ __forceinline__ float bf2f(unsigned short h) {
    return __uint_as_float(((unsigned)h) << 16);
}
__device__ __forceinline__ int pk(unsigned short lo, unsigned short hi) {
    return (int)((unsigned)lo | ((unsigned)hi << 16));
}

// ---------------- Kernel 1: pack A-style + B-style for both clouds --------
__device__ __forceinline__ void pack_point(const float* __restrict__ cloud,
                                           int b, int j, int gid,
                                           char* __restrict__ apack,
                                           char* __restrict__ bpack) {
    const unsigned short ONE = 0x3F80;
    const float* p = cloud + b * 3 * NPTS;
    const float x = p[j], y = p[NPTS + j], z = p[2 * NPTS + j];
    const unsigned short hx = f2bf(x), hy = f2bf(y), hz = f2bf(z);
    const unsigned short lx = f2bf(x - bf2f(hx));
    const unsigned short ly = f2bf(y - bf2f(hy));
    const unsigned short lz = f2bf(z - bf2f(hz));
    const unsigned short a0 = f2bf(-2.0f * bf2f(hx));
    const unsigned short a1 = f2bf(-2.0f * bf2f(hy));
    const unsigned short a2 = f2bf(-2.0f * bf2f(hz));
    const unsigned short m0 = f2bf(-2.0f * (x - bf2f(hx)));
    const unsigned short m1 = f2bf(-2.0f * (y - bf2f(hy)));
    const unsigned short m2 = f2bf(-2.0f * (z - bf2f(hz)));
    const float n2 = fmaf(z, z, fmaf(y, y, x * x));
    const unsigned short n2h = f2bf(n2);
    const unsigned short n2l = f2bf(n2 - bf2f(n2h));

    int4* Ap = (int4*)(apack + (size_t)gid * 32);
    Ap[0] = make_int4(pk(a0, a1), pk(a2, m0), pk(m1, m2), pk(a0, a1));
    Ap[1] = make_int4(pk(a2, n2h), pk(n2l, ONE), pk(ONE, 0), 0);

    int4* Bp = (int4*)(bpack + (size_t)gid * 32);
    Bp[0] = make_int4(pk(hx, hy), pk(hz, hx), pk(hy, hz), pk(lx, ly));
    Bp[1] = make_int4(pk(lz, ONE), pk(ONE, n2h), pk(n2l, 0), 0);
}

__global__ __launch_bounds__(256)
void transform_kernel(const float* __restrict__ srcs,
                      const float* __restrict__ tgts,
                      char* __restrict__ ws) {
    const int gid = blockIdx.x * 256 + threadIdx.x;   // b*4096 + j
    const int b = gid >> 12, j = gid & 4095;
    pack_point(srcs, b, j, gid, ws + OFF_APACK_S, ws + OFF_BPACK_S);
    pack_point(tgts, b, j, gid, ws + OFF_APACK_T, ws + OFF_BPACK_T);
}

// ---------------- Kernel 2: row-min-only MFMA chamfer ----------------
__global__ __launch_bounds__(512, 4)
void chamfer_kernel(char* __restrict__ ws) {
    const int blk    = blockIdx.x;        // 0..1023
    const int dir    = blk >> 9;
    const int rem    = blk & 511;
    const int b      = rem >> 6;
    const int stripe = rem & 63;          // 64 query rows
    const int tid    = threadIdx.x;
    const int wave   = tid >> 6;          // 0..7
    const int lane   = tid & 63;
    const int l31    = lane & 31;
    const int half   = lane >> 5;

    const char* Ap = ws + (dir == 0 ? OFF_APACK_S : OFF_APACK_T);
    const char* Bp = ws + (dir == 0 ? OFF_BPACK_T : OFF_BPACK_S);

    V16 av0, av1;
    av0.i = *(const int4*)(Ap + (size_t)(b * NPTS + stripe * 64 + l31) * 32 + half * 16);
    av1.i = *(const int4*)(Ap + (size_t)(b * NPTS + stripe * 64 + 32 + l31) * 32 + half * 16);

    floatx16 rmin0, rmin1, zero;
#pragma unroll
    for (int r = 0; r < 16; r++) { rmin0[r] = 3.0e38f; rmin1[r] = 3.0e38f; zero[r] = 0.0f; }

    const int ct0 = wave * 16;            // 16 col-tiles per wave
    const char* bbase = Bp + (size_t)(b * NPTS + ct0 * 32 + l31) * 32 + half * 16;

    // depth-4 register prefetch ring; wrap (&15) reloads L0-hot head at tail
    V16 t0, t1, t2, t3;
    t0.i = *(const int4*)(bbase);
    t1.i = *(const int4*)(bbase + 1024);
    t2.i = *(const int4*)(bbase + 2048);
    t3.i = *(const int4*)(bbase + 3072);

#pragma unroll
    for (int i = 0; i < 16; i += 4) {
        V16 n0, n1, n2, n3;
        n0.i = *(const int4*)(bbase + (size_t)((i + 4) & 15) * 1024);
        n1.i = *(const int4*)(bbase + (size_t)((i + 5) & 15) * 1024);
        n2.i = *(const int4*)(bbase + (size_t)((i + 6) & 15) * 1024);
        n3.i = *(const int4*)(bbase + (size_t)((i + 7) & 15) * 1024);
#pragma unroll
        for (int u = 0; u < 4; u++) {
            const bf16x8 bf = (u == 0 ? t0.h : u == 1 ? t1.h : u == 2 ? t2.h : t3.h);
            const floatx16 d0 =
                __builtin_amdgcn_mfma_f32_32x32x16_bf16(av0.h, bf, zero, 0, 0, 0);
            const floatx16 d1 =
                __builtin_amdgcn_mfma_f32_32x32x16_bf16(av1.h, bf, zero, 0, 0, 0);
#pragma unroll
            for (int r = 0; r < 16; r++) {
                rmin0[r] = fminf(rmin0[r], d0[r]);
                rmin1[r] = fminf(rmin1[r], d1[r]);
            }
        }
        t0 = n0; t1 = n1; t2 = n2; t3 = n3;
    }

    // ---- butterfly min over the 32 col-lanes ----
#pragma unroll
    for (int off = 1; off < 32; off <<= 1) {
#pragma unroll
        for (int r = 0; r < 16; r++) {
            rmin0[r] = fminf(rmin0[r], __shfl_xor(rmin0[r], off, 64));
            rmin1[r] = fminf(rmin1[r], __shfl_xor(rmin1[r], off, 64));
        }
    }
    __shared__ float sRow[8][64];
    if (l31 == 0) {                       // lanes 0 and 32
#pragma unroll
        for (int r = 0; r < 16; r++) {
            const int row = (r & 3) + 8 * (r >> 2) + 4 * half;
            sRow[wave][row]      = rmin0[r];
            sRow[wave][32 + row] = rmin1[r];
        }
    }
    __syncthreads();
    if (tid < 64) {
        float m = 3.0e38f;
#pragma unroll
        for (int w = 0; w < 8; w++) m = fminf(m, sRow[w][tid]);
        m = fmaxf(m, 0.0f);
        float g = m / (m + 1.0f);         // GM, MU=1
#pragma unroll
        for (int off = 1; off < 64; off <<= 1)
            g += __shfl_xor(g, off, 64);
        if (tid == 0)
            ((float*)(ws + OFF_BSUM))[blk] = g;   // plain store, no atomics
    }
}

// ---------------- Kernel 3: single-block finish ----------------
__global__ __launch_bounds__(256)
void finish_kernel(const char* __restrict__ ws, float* __restrict__ out) {
    const float* bsum = (const float*)(ws + OFF_BSUM);
    const int tid = threadIdx.x;
    float g = bsum[tid] + bsum[tid + 256] + bsum[tid + 512] + bsum[tid + 768];
#pragma unroll
    for (int off = 1; off < 64; off <<= 1)
        g += __shfl_xor(g, off, 64);
    __shared__ float sp[4];
    if ((tid & 63) == 0) sp[tid >> 6] = g;
    __syncthreads();
    if (tid == 0)
        out[0] = (sp[0] + sp[1] + sp[2] + sp[3]) * (1.0f / (NB * NPTS));
}

extern "C" void kernel_launch(void* const* d_in, const int* in_sizes, int n_in,
                              void* d_out, int out_size, void* d_ws, size_t ws_size,
                              hipStream_t stream) {
    const float* srcs = (const float*)d_in[0];
    const float* tgts = (const float*)d_in[1];
    float* out = (float*)d_out;
    char* ws = (char*)d_ws;

    transform_kernel<<<dim3(128), dim3(256), 0, stream>>>(srcs, tgts, ws);
    chamfer_kernel<<<dim3(1024), dim3(512), 0, stream>>>(ws);
    finish_kernel<<<dim3(1), dim3(256), 0, stream>>>(ws, out);
}